// Round 1
// baseline (2282.762 us; speedup 1.0000x reference)
//
#include <hip/hip_runtime.h>
#include <hip/hip_bf16.h>
#include <math.h>

#define T_ 512
#define N_ 32
#define D_ 300
#define R_ 3
#define E_ 64
#define VG_ 40000

// ---------------- small prep kernels ----------------
__global__ void k_zero(float* __restrict__ p, int n) {
  int i = blockIdx.x * blockDim.x + threadIdx.x;
  if (i < n) p[i] = 0.f;
}

__global__ void k_prep_uu(const float* __restrict__ Uu, unsigned short* __restrict__ ub, int n) {
  int i = blockIdx.x * blockDim.x + threadIdx.x;
  if (i < n) {
    __hip_bfloat16 h = __float2bfloat16(Uu[i]);
    ub[i] = *(unsigned short*)&h;
  }
}

// ---------------- gather + per-(t,r) node-0 aggregation ----------------
// xg[t][n*300+d] = X[idx[t,n]][d]
// Ag[t][r*300+d] = sum over edges into node0 (incl self loop) of norm * x[src][d]
// Ag[t][900+d]   = x[0][d]
__global__ void k_gather(const int* __restrict__ xidx, const int* __restrict__ esrc,
                         const int* __restrict__ edst, const float* __restrict__ X,
                         float* __restrict__ xg, float* __restrict__ Ag)
{
  const int t = blockIdx.x;
  __shared__ int s_idx[N_];
  __shared__ int s_src[R_][E_];
  __shared__ int s_dst[R_][E_];
  __shared__ int s_deg[R_][N_];
  __shared__ float s_dinv[R_][N_];
  const int tid = threadIdx.x;

  if (tid < N_) s_idx[tid] = xidx[t * N_ + tid];
  if (tid < R_ * E_) {
    int r = tid / E_, e = tid % E_;
    s_src[r][e] = esrc[(t * R_ + r) * E_ + e];
    s_dst[r][e] = edst[(t * R_ + r) * E_ + e];
  }
  if (tid < R_ * N_) ((int*)s_deg)[tid] = 1;  // self loop
  __syncthreads();
  if (tid < R_ * E_) {
    int r = tid / E_;
    atomicAdd(&s_deg[r][s_dst[r][tid % E_]], 1);
  }
  __syncthreads();
  if (tid < R_ * N_) ((float*)s_dinv)[tid] = rsqrtf((float)((int*)s_deg)[tid]);
  __syncthreads();

  for (int nd = tid; nd < N_ * D_; nd += blockDim.x) {
    int n = nd / D_, d = nd % D_;
    xg[(size_t)t * (N_ * D_) + nd] = X[(size_t)s_idx[n] * D_ + d];
  }
  if (tid < D_) {
    int d = tid;
    float x0 = X[(size_t)s_idx[0] * D_ + d];
    #pragma unroll
    for (int r = 0; r < R_; ++r) {
      float dinv0 = s_dinv[r][0];
      float acc = dinv0 * dinv0 * x0;  // self loop
      for (int e = 0; e < E_; ++e) {
        if (s_dst[r][e] == 0) {
          int s = s_src[r][e];
          acc += s_dinv[r][s] * dinv0 * X[(size_t)s_idx[s] * D_ + d];
        }
      }
      Ag[(size_t)t * 1200 + r * D_ + d] = acc;
    }
    Ag[(size_t)t * 1200 + 900 + d] = x0;
  }
}

// ---------------- generic fp32 tiled GEMM: C (+)= A[M,K] @ B ----------------
// TRANSB=false: B is [K,N] row-major; TRANSB=true: B is [N,K] row-major.
// grid = (M/64, ceil(N/64), ksplit); ATOMIC=true accumulates with atomicAdd (C pre-zeroed).
// M must be a multiple of 64 (512 here).
template<bool TRANSB, bool ATOMIC>
__global__ __launch_bounds__(256) void k_gemm(
    const float* __restrict__ A, int lda,
    const float* __restrict__ B, int ldb,
    const float* __restrict__ bias,
    float* __restrict__ C, int ldc,
    int M, int N, int K, int kchunk)
{
  __shared__ float As[16][68];
  __shared__ float Bs[16][68];
  const int bm = blockIdx.x * 64;
  const int bn = blockIdx.y * 64;
  const int k0 = blockIdx.z * kchunk;
  const int kend = min(K, k0 + kchunk);
  const int tid = threadIdx.x;
  const int tx = tid & 15, ty = tid >> 4;
  float acc[4][4];
  #pragma unroll
  for (int i = 0; i < 4; ++i)
    #pragma unroll
    for (int j = 0; j < 4; ++j) acc[i][j] = 0.f;

  for (int kb = k0; kb < kend; kb += 16) {
    {  // A tile: 64(m) x 16(k)
      int m = tid >> 2;
      int k4 = (tid & 3) * 4;
      const float* ap = A + (size_t)(bm + m) * lda + kb + k4;
      #pragma unroll
      for (int i = 0; i < 4; ++i)
        As[k4 + i][m] = (kb + k4 + i < kend) ? ap[i] : 0.f;
    }
    if (!TRANSB) {  // B tile from [K,N]
      int k = tid >> 4;
      int n4 = (tid & 15) * 4;
      const float* bp = B + (size_t)(kb + k) * ldb + bn + n4;
      bool kok = (kb + k < kend);
      #pragma unroll
      for (int i = 0; i < 4; ++i)
        Bs[k][n4 + i] = (kok && (bn + n4 + i < N)) ? bp[i] : 0.f;
    } else {        // B tile from [N,K]
      int n = tid >> 2;
      int k4 = (tid & 3) * 4;
      const float* bp = B + (size_t)(bn + n) * ldb + kb + k4;
      bool nok = (bn + n < N);
      #pragma unroll
      for (int i = 0; i < 4; ++i)
        Bs[k4 + i][n] = (nok && (kb + k4 + i < kend)) ? bp[i] : 0.f;
    }
    __syncthreads();
    #pragma unroll
    for (int kk = 0; kk < 16; ++kk) {
      float a0 = As[kk][ty * 4 + 0], a1 = As[kk][ty * 4 + 1];
      float a2 = As[kk][ty * 4 + 2], a3 = As[kk][ty * 4 + 3];
      float b0 = Bs[kk][tx * 4 + 0], b1 = Bs[kk][tx * 4 + 1];
      float b2 = Bs[kk][tx * 4 + 2], b3 = Bs[kk][tx * 4 + 3];
      acc[0][0] = fmaf(a0, b0, acc[0][0]); acc[0][1] = fmaf(a0, b1, acc[0][1]);
      acc[0][2] = fmaf(a0, b2, acc[0][2]); acc[0][3] = fmaf(a0, b3, acc[0][3]);
      acc[1][0] = fmaf(a1, b0, acc[1][0]); acc[1][1] = fmaf(a1, b1, acc[1][1]);
      acc[1][2] = fmaf(a1, b2, acc[1][2]); acc[1][3] = fmaf(a1, b3, acc[1][3]);
      acc[2][0] = fmaf(a2, b0, acc[2][0]); acc[2][1] = fmaf(a2, b1, acc[2][1]);
      acc[2][2] = fmaf(a2, b2, acc[2][2]); acc[2][3] = fmaf(a2, b3, acc[2][3]);
      acc[3][0] = fmaf(a3, b0, acc[3][0]); acc[3][1] = fmaf(a3, b1, acc[3][1]);
      acc[3][2] = fmaf(a3, b2, acc[3][2]); acc[3][3] = fmaf(a3, b3, acc[3][3]);
    }
    __syncthreads();
  }
  #pragma unroll
  for (int i = 0; i < 4; ++i) {
    int row = bm + ty * 4 + i;
    #pragma unroll
    for (int j = 0; j < 4; ++j) {
      int col = bn + tx * 4 + j;
      if (col < N) {
        float v = acc[i][j];
        if (bias) v += bias[col];
        if (ATOMIC) atomicAdd(&C[(size_t)row * ldc + col], v);
        else        C[(size_t)row * ldc + col] = v;
      }
    }
  }
}

// ---------------- sequential recurrence (single workgroup) ----------------
// m (300, fp32, LDS); per step: z = gx_t + m@Uu; g=sigmoid(z); m = g*P0_t+(1-g)*m;
// Mrelu[t] = relu(m). Uu held bf16 in LDS for rows < rows_lds, else global bf16.
__global__ __launch_bounds__(1024) void k_rec(
    const float* __restrict__ gx, const float* __restrict__ P0,
    const unsigned short* __restrict__ uuB, float* __restrict__ Mrelu,
    int rows_lds)
{
  extern __shared__ char sm[];
  float*  m_s  = (float*)sm;                       // 300 floats
  float2* zp   = (float2*)(sm + 1200);             // 6 x 150 float2
  unsigned short* uu_s = (unsigned short*)(sm + 1200 + 7200);
  const int tid = threadIdx.x;

  {  // stage Uu rows [0, rows_lds) into LDS (bf16, row-major [i][j])
    unsigned int* d32 = (unsigned int*)uu_s;
    const unsigned int* s32 = (const unsigned int*)uuB;
    int nw = rows_lds * (D_ / 2);
    for (int w = tid; w < nw; w += blockDim.x) d32[w] = s32[w];
  }
  if (tid < D_) m_s[tid] = 0.f;
  __syncthreads();

  for (int t = 0; t < T_; ++t) {
    if (tid < 900) {
      int c = tid / 150, jp = tid % 150;   // thread owns columns {2jp, 2jp+1}, i-chunk c
      float ax = 0.f, ay = 0.f;
      int i0 = c * 50;
      for (int i = i0; i < i0 + 50; ++i) {
        float mi = m_s[i];
        unsigned int u;
        if (i < rows_lds) u = *(const unsigned int*)(uu_s + i * D_ + 2 * jp);
        else              u = *(const unsigned int*)(uuB  + i * D_ + 2 * jp);
        float f0 = __uint_as_float(u << 16);
        float f1 = __uint_as_float(u & 0xffff0000u);
        ax = fmaf(f0, mi, ax);
        ay = fmaf(f1, mi, ay);
      }
      zp[c * 150 + jp] = make_float2(ax, ay);
    }
    __syncthreads();
    if (tid < 150) {
      int jp = tid;
      float zx = 0.f, zy = 0.f;
      #pragma unroll
      for (int c = 0; c < 6; ++c) { float2 v = zp[c * 150 + jp]; zx += v.x; zy += v.y; }
      zx += gx[(size_t)t * D_ + 2 * jp];
      zy += gx[(size_t)t * D_ + 2 * jp + 1];
      float gxv = 1.f / (1.f + expf(-zx));
      float gyv = 1.f / (1.f + expf(-zy));
      float p0x = P0[(size_t)t * D_ + 2 * jp], p0y = P0[(size_t)t * D_ + 2 * jp + 1];
      float mox = m_s[2 * jp], moy = m_s[2 * jp + 1];
      float mnx = gxv * p0x + (1.f - gxv) * mox;
      float mny = gyv * p0y + (1.f - gyv) * moy;
      m_s[2 * jp] = mnx; m_s[2 * jp + 1] = mny;
      Mrelu[(size_t)t * D_ + 2 * jp]     = fmaxf(mnx, 0.f);
      Mrelu[(size_t)t * D_ + 2 * jp + 1] = fmaxf(mny, 0.f);
    }
    __syncthreads();
  }
}

// ---------------- in-place log_softmax per row + tail zeros ----------------
__global__ __launch_bounds__(256) void k_lsm(float* __restrict__ out) {
  const int t = blockIdx.x;
  float* row = out + (size_t)t * VG_;
  __shared__ float redM[256];
  __shared__ float redS[256];
  const int tid = threadIdx.x;
  float lm = -1e30f, ls = 0.f;
  for (int v = tid; v < VG_; v += 256) {
    float z = row[v];
    float m2 = fmaxf(lm, z);
    ls = ls * expf(lm - m2) + expf(z - m2);
    lm = m2;
  }
  redM[tid] = lm; redS[tid] = ls;
  __syncthreads();
  for (int s = 128; s > 0; s >>= 1) {
    if (tid < s) {
      float mA = redM[tid], mB = redM[tid + s];
      float M = fmaxf(mA, mB);
      redS[tid] = redS[tid] * expf(mA - M) + redS[tid + s] * expf(mB - M);
      redM[tid] = M;
    }
    __syncthreads();
  }
  float lse = redM[0] + logf(redS[0]);
  for (int v = tid; v < VG_; v += 256) row[v] = row[v] - lse;
  if (tid == 0) out[(size_t)T_ * VG_ + t] = 0.0f;  // int32 zeros == fp32 0.0 bitwise
}

// ---------------- launch ----------------
extern "C" void kernel_launch(void* const* d_in, const int* in_sizes, int n_in,
                              void* d_out, int out_size, void* d_ws, size_t ws_size,
                              hipStream_t stream) {
  const int*   xidx  = (const int*)d_in[0];
  const int*   esrc  = (const int*)d_in[1];
  const int*   edst  = (const int*)d_in[2];
  const float* X     = (const float*)d_in[3];
  const float* convW = (const float*)d_in[4];
  const float* W0    = (const float*)d_in[5];
  const float* Wu    = (const float*)d_in[6];
  const float* Uu    = (const float*)d_in[7];
  const float* Wg    = (const float*)d_in[8];
  const float* bg    = (const float*)d_in[9];
  float* out = (float*)d_out;

  // workspace layout (floats)
  float* ws = (float*)d_ws;
  float* xg    = ws;                            // [512][9600]
  float* Ag    = xg + (size_t)T_ * N_ * D_;     // [512][1200]
  float* gx    = Ag + (size_t)T_ * 1200;        // [512][300]
  float* P0    = gx + (size_t)T_ * D_;          // [512][300]
  float* Mrelu = P0 + (size_t)T_ * D_;          // [512][300]
  unsigned short* UuB = (unsigned short*)(Mrelu + (size_t)T_ * D_);  // 90000 bf16

  // zero gx and P0 (contiguous)
  k_zero<<<(2 * T_ * D_ + 255) / 256, 256, 0, stream>>>(gx, 2 * T_ * D_);
  k_prep_uu<<<(D_ * D_ + 255) / 256, 256, 0, stream>>>(Uu, UuB, D_ * D_);
  k_gather<<<T_, 320, 0, stream>>>(xidx, esrc, edst, X, xg, Ag);

  // gx = xg @ Wu   [512,9600]@[9600,300], K-split 8
  k_gemm<false, true><<<dim3(8, 5, 8), 256, 0, stream>>>(
      xg, N_ * D_, Wu, D_, nullptr, gx, D_, T_, D_, N_ * D_, 1200);
  // P0 = Ag[:,:900] @ convW + Ag[:,900:] @ W0
  k_gemm<false, true><<<dim3(8, 5, 1), 256, 0, stream>>>(
      Ag, 1200, convW, D_, nullptr, P0, D_, T_, D_, 900, 900);
  k_gemm<false, true><<<dim3(8, 5, 1), 256, 0, stream>>>(
      Ag + 900, 1200, W0, D_, nullptr, P0, D_, T_, D_, 300, 304);

  // sequential recurrence: try 160KB LDS opt-in, else 64KB fallback
  int rows = 252;
  size_t smem = 1200 + 7200 + (size_t)rows * D_ * 2;  // 159,600 B
  hipError_t e = hipFuncSetAttribute((const void*)k_rec,
                                     hipFuncAttributeMaxDynamicSharedMemorySize,
                                     (int)smem);
  if (e != hipSuccess) {
    rows = 93;
    smem = 1200 + 7200 + (size_t)rows * D_ * 2;       // 64,200 B
  }
  (void)hipGetLastError();
  k_rec<<<1, 1024, smem, stream>>>(gx, P0, UuB, Mrelu, rows);

  // logits = Mrelu @ Wg^T + bg -> d_out, then in-place log_softmax
  k_gemm<true, false><<<dim3(8, 625, 1), 256, 0, stream>>>(
      Mrelu, D_, Wg, D_, bg, out, VG_, T_, VG_, D_, 304);
  k_lsm<<<T_, 256, 0, stream>>>(out);
}

// Round 2
// 949.275 us; speedup vs baseline: 2.4047x; 2.4047x over previous
//
#include <hip/hip_runtime.h>
#include <hip/hip_bf16.h>
#include <math.h>

#define T_ 512
#define N_ 32
#define D_ 300
#define R_ 3
#define E_ 64
#define VG_ 40000

typedef __attribute__((ext_vector_type(8))) short bf16x8;
typedef __attribute__((ext_vector_type(4))) float f32x4;

static __device__ inline unsigned short f2b(float f) {
  __hip_bfloat16 h = __float2bfloat16(f);
  return *(unsigned short*)&h;
}

// ---------------- zero ----------------
__global__ void k_zero(float* __restrict__ p, int n) {
  int i = blockIdx.x * blockDim.x + threadIdx.x;
  if (i < n) p[i] = 0.f;
}

// ---------------- transpose Wu [9600,300] -> Wu_t bf16 [384][9600] ----------------
__global__ void k_tr_wu(const float* __restrict__ Wu, unsigned short* __restrict__ Wt) {
  __shared__ float s[32][33];
  int kb = blockIdx.x * 32, nb = blockIdx.y * 32;
  int tn = threadIdx.x & 31, tr = threadIdx.x >> 5;  // 256 threads: tr 0..7
  for (int i = tr; i < 32; i += 8) {
    int k = kb + i, n = nb + tn;
    s[i][tn] = (n < 300) ? Wu[(size_t)k * 300 + n] : 0.f;
  }
  __syncthreads();
  for (int i = tr; i < 32; i += 8) {
    int n = nb + i, k = kb + tn;
    Wt[(size_t)n * 9600 + k] = f2b(s[tn][i]);
  }
}

// ---------------- transpose [convW;W0] [1200,300] -> Wcat_t bf16 [384][1216] ----------------
__global__ void k_tr_wcat(const float* __restrict__ convW, const float* __restrict__ W0,
                          unsigned short* __restrict__ Wt) {
  __shared__ float s[32][33];
  int kb = blockIdx.x * 32, nb = blockIdx.y * 32;
  int tn = threadIdx.x & 31, tr = threadIdx.x >> 5;
  for (int i = tr; i < 32; i += 8) {
    int k = kb + i, n = nb + tn;
    float v = 0.f;
    if (n < 300 && k < 1200)
      v = (k < 900) ? convW[(size_t)k * 300 + n] : W0[(size_t)(k - 900) * 300 + n];
    s[i][tn] = v;
  }
  __syncthreads();
  for (int i = tr; i < 32; i += 8) {
    int n = nb + i, k = kb + tn;
    Wt[(size_t)n * 1216 + k] = f2b(s[tn][i]);
  }
}

// ---------------- gather + node-0 aggregation (bf16 outputs) ----------------
__global__ void k_gather(const int* __restrict__ xidx, const int* __restrict__ esrc,
                         const int* __restrict__ edst, const float* __restrict__ X,
                         unsigned short* __restrict__ xg, unsigned short* __restrict__ Ag)
{
  const int t = blockIdx.x;
  __shared__ int s_idx[N_];
  __shared__ int s_src[R_][E_];
  __shared__ int s_dst[R_][E_];
  __shared__ int s_deg[R_][N_];
  __shared__ float s_dinv[R_][N_];
  const int tid = threadIdx.x;

  if (tid < N_) s_idx[tid] = xidx[t * N_ + tid];
  if (tid < R_ * E_) {
    int r = tid / E_, e = tid % E_;
    s_src[r][e] = esrc[(t * R_ + r) * E_ + e];
    s_dst[r][e] = edst[(t * R_ + r) * E_ + e];
  }
  if (tid < R_ * N_) ((int*)s_deg)[tid] = 1;  // self loop
  __syncthreads();
  if (tid < R_ * E_) {
    int r = tid / E_;
    atomicAdd(&s_deg[r][s_dst[r][tid % E_]], 1);
  }
  __syncthreads();
  if (tid < R_ * N_) ((float*)s_dinv)[tid] = rsqrtf((float)((int*)s_deg)[tid]);
  __syncthreads();

  for (int nd = tid; nd < N_ * D_; nd += blockDim.x) {
    int n = nd / D_, d = nd % D_;
    xg[(size_t)t * (N_ * D_) + nd] = f2b(X[(size_t)s_idx[n] * D_ + d]);
  }
  if (tid < D_) {
    int d = tid;
    float x0 = X[(size_t)s_idx[0] * D_ + d];
    #pragma unroll
    for (int r = 0; r < R_; ++r) {
      float dinv0 = s_dinv[r][0];
      float acc = dinv0 * dinv0 * x0;  // self loop
      for (int e = 0; e < E_; ++e) {
        if (s_dst[r][e] == 0) {
          int s = s_src[r][e];
          acc += s_dinv[r][s] * dinv0 * X[(size_t)s_idx[s] * D_ + d];
        }
      }
      Ag[(size_t)t * 1216 + r * D_ + d] = f2b(acc);
    }
    Ag[(size_t)t * 1216 + 900 + d] = f2b(x0);
  }
  if (tid < 16) Ag[(size_t)t * 1216 + 1200 + tid] = 0;  // K pad to 1216
}

// ---------------- bf16 MFMA GEMM: C (+)= A[M][K]bf16 @ B^T (B [Npad][K] bf16) ----------------
// grid (M/128, ceil(Ncols/128), ksplit); block 256 (4 waves, 2x2 of 64x64).
template<bool ATOMIC>
__global__ __launch_bounds__(256) void k_bgemm(
    const unsigned short* __restrict__ A,
    const unsigned short* __restrict__ B,
    float* __restrict__ C, int ldc, int Ncols, int K, int kchunk)
{
  const int tid = threadIdx.x;
  const int wid = tid >> 6, lane = tid & 63;
  const int l16 = lane & 15, lq = lane >> 4;
  const int bm = blockIdx.x * 128 + (wid & 1) * 64;
  const int bn = blockIdx.y * 128 + (wid >> 1) * 64;
  const int k0 = blockIdx.z * kchunk;
  const int nk = kchunk / 32;

  f32x4 acc[4][4] = {};
  const unsigned short* ap[4];
  const unsigned short* bp[4];
  #pragma unroll
  for (int mt = 0; mt < 4; ++mt) ap[mt] = A + (size_t)(bm + mt * 16 + l16) * K + k0 + lq * 8;
  #pragma unroll
  for (int nt = 0; nt < 4; ++nt) bp[nt] = B + (size_t)(bn + nt * 16 + l16) * K + k0 + lq * 8;

  #pragma unroll 2
  for (int c = 0; c < nk; ++c) {
    bf16x8 af[4], bfr[4];
    #pragma unroll
    for (int mt = 0; mt < 4; ++mt) af[mt] = *(const bf16x8*)(ap[mt] + c * 32);
    #pragma unroll
    for (int nt = 0; nt < 4; ++nt) bfr[nt] = *(const bf16x8*)(bp[nt] + c * 32);
    #pragma unroll
    for (int mt = 0; mt < 4; ++mt)
      #pragma unroll
      for (int nt = 0; nt < 4; ++nt)
        acc[mt][nt] = __builtin_amdgcn_mfma_f32_16x16x32_bf16(af[mt], bfr[nt], acc[mt][nt], 0, 0, 0);
  }

  #pragma unroll
  for (int mt = 0; mt < 4; ++mt) {
    #pragma unroll
    for (int r = 0; r < 4; ++r) {
      int row = bm + mt * 16 + lq * 4 + r;
      #pragma unroll
      for (int nt = 0; nt < 4; ++nt) {
        int col = bn + nt * 16 + l16;
        if (col < Ncols) {
          if (ATOMIC) atomicAdd(&C[(size_t)row * ldc + col], acc[mt][nt][r]);
          else        C[(size_t)row * ldc + col] = acc[mt][nt][r];
        }
      }
    }
  }
}

// ---------------- logits GEMM: out[512][40000] = Mrelu_bf[512][320] @ Wg^T + bg ----------------
__global__ __launch_bounds__(256) void k_lgemm(
    const unsigned short* __restrict__ A, const float* __restrict__ Wg,
    const float* __restrict__ bg, float* __restrict__ C)
{
  const int tid = threadIdx.x;
  const int wid = tid >> 6, lane = tid & 63;
  const int l16 = lane & 15, lq = lane >> 4;
  const int bm = blockIdx.x * 128 + (wid & 1) * 64;
  const int bn = blockIdx.y * 128 + (wid >> 1) * 64;

  f32x4 acc[4][4] = {};
  const unsigned short* ap[4];
  const float* bp[4];
  #pragma unroll
  for (int mt = 0; mt < 4; ++mt) ap[mt] = A + (size_t)(bm + mt * 16 + l16) * 320 + lq * 8;
  #pragma unroll
  for (int nt = 0; nt < 4; ++nt) {
    int r = bn + nt * 16 + l16;
    if (r > VG_ - 1) r = VG_ - 1;  // clamp: OOB cols never written
    bp[nt] = Wg + (size_t)r * 300;
  }

  #pragma unroll
  for (int c = 0; c < 10; ++c) {
    bf16x8 af[4], bfr[4];
    #pragma unroll
    for (int mt = 0; mt < 4; ++mt) af[mt] = *(const bf16x8*)(ap[mt] + c * 32);
    if (c < 9) {
      #pragma unroll
      for (int nt = 0; nt < 4; ++nt) {
        f32x4 x = *(const f32x4*)(bp[nt] + c * 32 + lq * 8);
        f32x4 y = *(const f32x4*)(bp[nt] + c * 32 + lq * 8 + 4);
        bf16x8 bv;
        #pragma unroll
        for (int j = 0; j < 4; ++j) { bv[j] = (short)f2b(x[j]); bv[4 + j] = (short)f2b(y[j]); }
        bfr[nt] = bv;
      }
    } else {
      #pragma unroll
      for (int nt = 0; nt < 4; ++nt) {
        bf16x8 bv;
        #pragma unroll
        for (int j = 0; j < 8; ++j) {
          int k = 288 + lq * 8 + j;
          bv[j] = (short)((k < 300) ? f2b(bp[nt][k]) : 0);
        }
        bfr[nt] = bv;
      }
    }
    #pragma unroll
    for (int mt = 0; mt < 4; ++mt)
      #pragma unroll
      for (int nt = 0; nt < 4; ++nt)
        acc[mt][nt] = __builtin_amdgcn_mfma_f32_16x16x32_bf16(af[mt], bfr[nt], acc[mt][nt], 0, 0, 0);
  }

  #pragma unroll
  for (int mt = 0; mt < 4; ++mt) {
    #pragma unroll
    for (int r = 0; r < 4; ++r) {
      int row = bm + mt * 16 + lq * 4 + r;
      #pragma unroll
      for (int nt = 0; nt < 4; ++nt) {
        int col = bn + nt * 16 + l16;
        if (col < VG_)
          C[(size_t)row * VG_ + col] = acc[mt][nt][r] + bg[col];
      }
    }
  }
}

// ---------------- sequential recurrence: MFMA matvec, Uu fragments in registers ----------------
// block 640 (10 waves). Wave w owns n-tiles {2w, 2w+1} (wave 9: {18}).
// A = m replicated across 16 rows (bf16 in LDS); B = Uu[k][n] frags preloaded to VGPRs.
__global__ __launch_bounds__(640) void k_rec(
    const float* __restrict__ gx, const float* __restrict__ P0,
    const float* __restrict__ Uu, unsigned short* __restrict__ Mrelu_bf)
{
  __shared__ __align__(16) unsigned short m_bf[320];
  __shared__ float zs[304];
  __shared__ unsigned short mr_s[8 * 320];  // 8-step Mrelu batch
  const int tid = threadIdx.x;
  const int wid = tid >> 6, lane = tid & 63;
  const int l16 = lane & 15, lq = lane >> 4;
  const int nt0 = wid * 2, nt1 = wid * 2 + 1;
  const bool two = (nt1 < 19);

  // preload B fragments: b[tile][k-chunk], layout B[k=(lq*8+j)+32c][n=tile*16+l16]
  bf16x8 b0[10], b1[10];
  {
    int n0 = nt0 * 16 + l16, n1 = nt1 * 16 + l16;
    #pragma unroll
    for (int c = 0; c < 10; ++c) {
      bf16x8 v0, v1;
      #pragma unroll
      for (int j = 0; j < 8; ++j) {
        int k = c * 32 + lq * 8 + j;
        float f0 = (k < 300 && n0 < 300) ? Uu[(size_t)k * 300 + n0] : 0.f;
        float f1 = (two && k < 300 && n1 < 300) ? Uu[(size_t)k * 300 + n1] : 0.f;
        v0[j] = (short)f2b(f0);
        v1[j] = (short)f2b(f1);
      }
      b0[c] = v0; b1[c] = v1;
    }
  }

  float m_reg = 0.f;
  if (tid < 320) m_bf[tid] = 0;
  __syncthreads();

  for (int t = 0; t < T_; ++t) {
    float gxv = 0.f, p0v = 0.f;
    if (tid < 300) {  // prefetch; completes during MFMA phase
      gxv = gx[(size_t)t * D_ + tid];
      p0v = P0[(size_t)t * D_ + tid];
    }
    f32x4 acc0 = {0.f, 0.f, 0.f, 0.f}, acc1 = {0.f, 0.f, 0.f, 0.f};
    #pragma unroll
    for (int c = 0; c < 10; ++c) {
      bf16x8 a = *(const bf16x8*)(m_bf + c * 32 + lq * 8);  // broadcast read
      acc0 = __builtin_amdgcn_mfma_f32_16x16x32_bf16(a, b0[c], acc0, 0, 0, 0);
      if (two)
        acc1 = __builtin_amdgcn_mfma_f32_16x16x32_bf16(a, b1[c], acc1, 0, 0, 0);
    }
    if (lq == 0) {  // C row 0 lives in lanes 0..15, reg 0
      zs[nt0 * 16 + l16] = acc0[0];
      if (two) zs[nt1 * 16 + l16] = acc1[0];
    }
    __syncthreads();
    if (tid < 300) {
      float z = zs[tid] + gxv;
      float g = 1.f / (1.f + __expf(-z));
      m_reg = fmaf(g, p0v - m_reg, m_reg);   // g*p0 + (1-g)*m
      m_bf[tid] = f2b(m_reg);
      mr_s[(t & 7) * 320 + tid] = f2b(fmaxf(m_reg, 0.f));
    } else if (tid < 320) {
      mr_s[(t & 7) * 320 + tid] = 0;
    }
    __syncthreads();
    if ((t & 7) == 7) {  // flush 8 steps of Mrelu, coalesced
      unsigned int* dst = (unsigned int*)(Mrelu_bf + (size_t)(t - 7) * 320);
      const unsigned int* src = (const unsigned int*)mr_s;
      for (int w = tid; w < 1280; w += 640) dst[w] = src[w];
      // no barrier needed: mr_s slot (t&7) isn't rewritten until 8 steps later
    }
  }
}

// ---------------- in-place log_softmax per row + int32-zero tail ----------------
__global__ __launch_bounds__(256) void k_lsm(float* __restrict__ out) {
  const int t = blockIdx.x;
  float* row = out + (size_t)t * VG_;
  __shared__ float redM[256];
  __shared__ float redS[256];
  const int tid = threadIdx.x;
  float lm = -1e30f, ls = 0.f;
  for (int v = tid; v < VG_; v += 256) {
    float z = row[v];
    float m2 = fmaxf(lm, z);
    ls = ls * expf(lm - m2) + expf(z - m2);
    lm = m2;
  }
  redM[tid] = lm; redS[tid] = ls;
  __syncthreads();
  for (int s = 128; s > 0; s >>= 1) {
    if (tid < s) {
      float mA = redM[tid], mB = redM[tid + s];
      float M = fmaxf(mA, mB);
      redS[tid] = redS[tid] * expf(mA - M) + redS[tid + s] * expf(mB - M);
      redM[tid] = M;
    }
    __syncthreads();
  }
  float lse = redM[0] + logf(redS[0]);
  for (int v = tid; v < VG_; v += 256) row[v] = row[v] - lse;
  if (tid == 0) out[(size_t)T_ * VG_ + t] = 0.0f;
}

// ---------------- launch ----------------
extern "C" void kernel_launch(void* const* d_in, const int* in_sizes, int n_in,
                              void* d_out, int out_size, void* d_ws, size_t ws_size,
                              hipStream_t stream) {
  const int*   xidx  = (const int*)d_in[0];
  const int*   esrc  = (const int*)d_in[1];
  const int*   edst  = (const int*)d_in[2];
  const float* X     = (const float*)d_in[3];
  const float* convW = (const float*)d_in[4];
  const float* W0    = (const float*)d_in[5];
  const float* Wu    = (const float*)d_in[6];
  const float* Uu    = (const float*)d_in[7];
  const float* Wg    = (const float*)d_in[8];
  const float* bg    = (const float*)d_in[9];
  float* out = (float*)d_out;

  // workspace layout (20.94 MB total, all 16B-aligned)
  char* ws = (char*)d_ws;
  float*          gx     = (float*)ws;                              // 512*300 f32
  float*          P0     = (float*)(ws + 614400);                   // 512*300 f32
  unsigned short* MreluB = (unsigned short*)(ws + 1228800);         // 512*320 bf16
  unsigned short* xgB    = (unsigned short*)(ws + 1556480);         // 512*9600 bf16
  unsigned short* AgB    = (unsigned short*)(ws + 11386880);        // 512*1216 bf16
  unsigned short* WuT    = (unsigned short*)(ws + 12632064);        // 384*9600 bf16
  unsigned short* WcatT  = (unsigned short*)(ws + 20004864);        // 384*1216 bf16

  k_zero<<<(T_ * D_ + 255) / 256, 256, 0, stream>>>(gx, T_ * D_);
  k_tr_wu<<<dim3(300, 12), 256, 0, stream>>>(Wu, WuT);
  k_tr_wcat<<<dim3(38, 12), 256, 0, stream>>>(convW, W0, WcatT);
  k_gather<<<T_, 320, 0, stream>>>(xidx, esrc, edst, X, xgB, AgB);

  // gx = xg @ Wu   (split-K=10, atomic into zeroed gx)
  k_bgemm<true><<<dim3(4, 3, 10), 256, 0, stream>>>(xgB, WuT, gx, D_, D_, 9600, 960);
  // P0 = [Ag | x0] @ [convW; W0]
  k_bgemm<false><<<dim3(4, 3, 1), 256, 0, stream>>>(AgB, WcatT, P0, D_, D_, 1216, 1216);

  k_rec<<<1, 640, 0, stream>>>(gx, P0, Uu, MreluB);

  k_lgemm<<<dim3(4, 313), 256, 0, stream>>>(MreluB, Wg, bg, out);
  k_lsm<<<T_, 256, 0, stream>>>(out);
}

// Round 3
// 891.338 us; speedup vs baseline: 2.5611x; 1.0650x over previous
//
#include <hip/hip_runtime.h>
#include <hip/hip_bf16.h>
#include <math.h>

#define T_ 512
#define N_ 32
#define D_ 300
#define R_ 3
#define E_ 64
#define VG_ 40000

typedef __attribute__((ext_vector_type(8))) short bf16x8;
typedef __attribute__((ext_vector_type(4))) float f32x4;

// workgroup barrier that only drains LDS (lgkmcnt), NOT vmcnt:
// __syncthreads() emits s_waitcnt vmcnt(0) lgkmcnt(0) + s_barrier, which
// drains in-flight global prefetches/stores every step (the R2 stall).
#define LGKM_BARRIER() asm volatile("s_waitcnt lgkmcnt(0)\n\ts_barrier" ::: "memory")

static __device__ inline unsigned short f2b(float f) {
  __hip_bfloat16 h = __float2bfloat16(f);
  return *(unsigned short*)&h;
}

// ---------------- zero ----------------
__global__ void k_zero(float* __restrict__ p, int n) {
  int i = blockIdx.x * blockDim.x + threadIdx.x;
  if (i < n) p[i] = 0.f;
}

// ---------------- transpose Wu [9600,300] -> Wu_t bf16 [384][9600] ----------------
__global__ void k_tr_wu(const float* __restrict__ Wu, unsigned short* __restrict__ Wt) {
  __shared__ float s[32][33];
  int kb = blockIdx.x * 32, nb = blockIdx.y * 32;
  int tn = threadIdx.x & 31, tr = threadIdx.x >> 5;  // 256 threads: tr 0..7
  for (int i = tr; i < 32; i += 8) {
    int k = kb + i, n = nb + tn;
    s[i][tn] = (n < 300) ? Wu[(size_t)k * 300 + n] : 0.f;
  }
  __syncthreads();
  for (int i = tr; i < 32; i += 8) {
    int n = nb + i, k = kb + tn;
    Wt[(size_t)n * 9600 + k] = f2b(s[tn][i]);
  }
}

// ---------------- transpose [convW;W0] [1200,300] -> Wcat_t bf16 [384][1216] ----------------
__global__ void k_tr_wcat(const float* __restrict__ convW, const float* __restrict__ W0,
                          unsigned short* __restrict__ Wt) {
  __shared__ float s[32][33];
  int kb = blockIdx.x * 32, nb = blockIdx.y * 32;
  int tn = threadIdx.x & 31, tr = threadIdx.x >> 5;
  for (int i = tr; i < 32; i += 8) {
    int k = kb + i, n = nb + tn;
    float v = 0.f;
    if (n < 300 && k < 1200)
      v = (k < 900) ? convW[(size_t)k * 300 + n] : W0[(size_t)(k - 900) * 300 + n];
    s[i][tn] = v;
  }
  __syncthreads();
  for (int i = tr; i < 32; i += 8) {
    int n = nb + i, k = kb + tn;
    Wt[(size_t)n * 1216 + k] = f2b(s[tn][i]);
  }
}

// ---------------- gather + node-0 aggregation (bf16 outputs) ----------------
__global__ void k_gather(const int* __restrict__ xidx, const int* __restrict__ esrc,
                         const int* __restrict__ edst, const float* __restrict__ X,
                         unsigned short* __restrict__ xg, unsigned short* __restrict__ Ag)
{
  const int t = blockIdx.x;
  __shared__ int s_idx[N_];
  __shared__ int s_src[R_][E_];
  __shared__ int s_dst[R_][E_];
  __shared__ int s_deg[R_][N_];
  __shared__ float s_dinv[R_][N_];
  const int tid = threadIdx.x;

  if (tid < N_) s_idx[tid] = xidx[t * N_ + tid];
  if (tid < R_ * E_) {
    int r = tid / E_, e = tid % E_;
    s_src[r][e] = esrc[(t * R_ + r) * E_ + e];
    s_dst[r][e] = edst[(t * R_ + r) * E_ + e];
  }
  if (tid < R_ * N_) ((int*)s_deg)[tid] = 1;  // self loop
  __syncthreads();
  if (tid < R_ * E_) {
    int r = tid / E_;
    atomicAdd(&s_deg[r][s_dst[r][tid % E_]], 1);
  }
  __syncthreads();
  if (tid < R_ * N_) ((float*)s_dinv)[tid] = rsqrtf((float)((int*)s_deg)[tid]);
  __syncthreads();

  for (int nd = tid; nd < N_ * D_; nd += blockDim.x) {
    int n = nd / D_, d = nd % D_;
    xg[(size_t)t * (N_ * D_) + nd] = f2b(X[(size_t)s_idx[n] * D_ + d]);
  }
  if (tid < D_) {
    int d = tid;
    float x0 = X[(size_t)s_idx[0] * D_ + d];
    #pragma unroll
    for (int r = 0; r < R_; ++r) {
      float dinv0 = s_dinv[r][0];
      float acc = dinv0 * dinv0 * x0;  // self loop
      for (int e = 0; e < E_; ++e) {
        if (s_dst[r][e] == 0) {
          int s = s_src[r][e];
          acc += s_dinv[r][s] * dinv0 * X[(size_t)s_idx[s] * D_ + d];
        }
      }
      Ag[(size_t)t * 1216 + r * D_ + d] = f2b(acc);
    }
    Ag[(size_t)t * 1216 + 900 + d] = f2b(x0);
  }
  if (tid < 16) Ag[(size_t)t * 1216 + 1200 + tid] = 0;  // K pad to 1216
}

// ---------------- bf16 MFMA GEMM: C (+)= A[M][K]bf16 @ B^T (B [Npad][K] bf16) ----------------
template<bool ATOMIC>
__global__ __launch_bounds__(256) void k_bgemm(
    const unsigned short* __restrict__ A,
    const unsigned short* __restrict__ B,
    float* __restrict__ C, int ldc, int Ncols, int K, int kchunk)
{
  const int tid = threadIdx.x;
  const int wid = tid >> 6, lane = tid & 63;
  const int l16 = lane & 15, lq = lane >> 4;
  const int bm = blockIdx.x * 128 + (wid & 1) * 64;
  const int bn = blockIdx.y * 128 + (wid >> 1) * 64;
  const int k0 = blockIdx.z * kchunk;
  const int nk = kchunk / 32;

  f32x4 acc[4][4] = {};
  const unsigned short* ap[4];
  const unsigned short* bp[4];
  #pragma unroll
  for (int mt = 0; mt < 4; ++mt) ap[mt] = A + (size_t)(bm + mt * 16 + l16) * K + k0 + lq * 8;
  #pragma unroll
  for (int nt = 0; nt < 4; ++nt) bp[nt] = B + (size_t)(bn + nt * 16 + l16) * K + k0 + lq * 8;

  #pragma unroll 2
  for (int c = 0; c < nk; ++c) {
    bf16x8 af[4], bfr[4];
    #pragma unroll
    for (int mt = 0; mt < 4; ++mt) af[mt] = *(const bf16x8*)(ap[mt] + c * 32);
    #pragma unroll
    for (int nt = 0; nt < 4; ++nt) bfr[nt] = *(const bf16x8*)(bp[nt] + c * 32);
    #pragma unroll
    for (int mt = 0; mt < 4; ++mt)
      #pragma unroll
      for (int nt = 0; nt < 4; ++nt)
        acc[mt][nt] = __builtin_amdgcn_mfma_f32_16x16x32_bf16(af[mt], bfr[nt], acc[mt][nt], 0, 0, 0);
  }

  #pragma unroll
  for (int mt = 0; mt < 4; ++mt) {
    #pragma unroll
    for (int r = 0; r < 4; ++r) {
      int row = bm + mt * 16 + lq * 4 + r;
      #pragma unroll
      for (int nt = 0; nt < 4; ++nt) {
        int col = bn + nt * 16 + l16;
        if (col < Ncols) {
          if (ATOMIC) atomicAdd(&C[(size_t)row * ldc + col], acc[mt][nt][r]);
          else        C[(size_t)row * ldc + col] = acc[mt][nt][r];
        }
      }
    }
  }
}

// ---------------- logits GEMM: out[512][40000] = Mrelu_bf[512][320] @ Wg^T + bg ----------------
// Single pass over Wg: each block owns 64 cols and ALL 512 rows (8 m-tiles/wave).
__global__ __launch_bounds__(256, 2) void k_lgemm(
    const unsigned short* __restrict__ A, const float* __restrict__ Wg,
    const float* __restrict__ bg, float* __restrict__ C)
{
  const int tid = threadIdx.x;
  const int wid = tid >> 6, lane = tid & 63;
  const int l16 = lane & 15, lq = lane >> 4;
  const int bn = blockIdx.x * 64;
  const int m0 = wid * 128;

  f32x4 acc[8][4] = {};
  const unsigned short* ap[8];
  const float* bp[4];
  #pragma unroll
  for (int mt = 0; mt < 8; ++mt) ap[mt] = A + (size_t)(m0 + mt * 16 + l16) * 320 + lq * 8;
  #pragma unroll
  for (int nt = 0; nt < 4; ++nt) bp[nt] = Wg + (size_t)(bn + nt * 16 + l16) * 300;

  #pragma unroll
  for (int c = 0; c < 10; ++c) {
    bf16x8 bfr[4];
    if (c < 9) {
      #pragma unroll
      for (int nt = 0; nt < 4; ++nt) {
        f32x4 x = *(const f32x4*)(bp[nt] + c * 32 + lq * 8);
        f32x4 y = *(const f32x4*)(bp[nt] + c * 32 + lq * 8 + 4);
        bf16x8 bv;
        #pragma unroll
        for (int j = 0; j < 4; ++j) { bv[j] = (short)f2b(x[j]); bv[4 + j] = (short)f2b(y[j]); }
        bfr[nt] = bv;
      }
    } else {
      #pragma unroll
      for (int nt = 0; nt < 4; ++nt) {
        bf16x8 bv;
        #pragma unroll
        for (int j = 0; j < 8; ++j) {
          int k = 288 + lq * 8 + j;
          bv[j] = (short)((k < 300) ? f2b(bp[nt][k]) : 0);
        }
        bfr[nt] = bv;
      }
    }
    bf16x8 af[8];
    #pragma unroll
    for (int mt = 0; mt < 8; ++mt) af[mt] = *(const bf16x8*)(ap[mt] + c * 32);
    #pragma unroll
    for (int mt = 0; mt < 8; ++mt)
      #pragma unroll
      for (int nt = 0; nt < 4; ++nt)
        acc[mt][nt] = __builtin_amdgcn_mfma_f32_16x16x32_bf16(af[mt], bfr[nt], acc[mt][nt], 0, 0, 0);
  }

  float bb[4];
  #pragma unroll
  for (int nt = 0; nt < 4; ++nt) bb[nt] = bg[bn + nt * 16 + l16];
  #pragma unroll
  for (int mt = 0; mt < 8; ++mt) {
    #pragma unroll
    for (int r = 0; r < 4; ++r) {
      int row = m0 + mt * 16 + lq * 4 + r;
      #pragma unroll
      for (int nt = 0; nt < 4; ++nt) {
        int col = bn + nt * 16 + l16;
        C[(size_t)row * VG_ + col] = acc[mt][nt][r] + bb[nt];
      }
    }
  }
}

// ---------------- sequential recurrence: MFMA matvec, Uu fragments in registers ----------------
// block 640 (10 waves), wave w owns n-tiles {2w, 2w+1} (Npad=320, 20 tiles).
// lgkm-only barriers keep global prefetches/stores in flight across steps.
__global__ __launch_bounds__(640) void k_rec(
    const float* __restrict__ gx, const float* __restrict__ P0,
    const float* __restrict__ Uu, unsigned short* __restrict__ Mrelu_bf)
{
  __shared__ __align__(16) unsigned short m_bf[320];
  __shared__ float zs[320];
  __shared__ unsigned short mr_s[8 * 320];  // 8-step Mrelu batch
  const int tid = threadIdx.x;
  const int wid = tid >> 6, lane = tid & 63;
  const int l16 = lane & 15, lq = lane >> 4;
  const int nt0 = wid * 2, nt1 = wid * 2 + 1;

  // preload B fragments: layout B[k=(lq*8+j)+32c][n=tile*16+l16]
  bf16x8 b0[10], b1[10];
  {
    int n0 = nt0 * 16 + l16, n1 = nt1 * 16 + l16;
    #pragma unroll
    for (int c = 0; c < 10; ++c) {
      bf16x8 v0, v1;
      #pragma unroll
      for (int j = 0; j < 8; ++j) {
        int k = c * 32 + lq * 8 + j;
        float f0 = (k < 300 && n0 < 300) ? Uu[(size_t)k * 300 + n0] : 0.f;
        float f1 = (k < 300 && n1 < 300) ? Uu[(size_t)k * 300 + n1] : 0.f;
        v0[j] = (short)f2b(f0);
        v1[j] = (short)f2b(f1);
      }
      b0[c] = v0; b1[c] = v1;
    }
  }

  float m_reg = 0.f;
  if (tid < 320) m_bf[tid] = 0;
  float gx_cur = 0.f, p0_cur = 0.f, gx_nxt = 0.f, p0_nxt = 0.f;
  if (tid < 300) { gx_cur = gx[tid]; p0_cur = P0[tid]; }
  __syncthreads();

  for (int t = 0; t < T_; ++t) {
    if (tid < 300 && t + 1 < T_) {  // prefetch next step (consumed after next rotate)
      gx_nxt = gx[(size_t)(t + 1) * D_ + tid];
      p0_nxt = P0[(size_t)(t + 1) * D_ + tid];
    }
    f32x4 acc0 = {0.f, 0.f, 0.f, 0.f}, acc1 = {0.f, 0.f, 0.f, 0.f};
    #pragma unroll
    for (int c = 0; c < 10; ++c) {
      bf16x8 a = *(const bf16x8*)(m_bf + c * 32 + lq * 8);  // broadcast read
      acc0 = __builtin_amdgcn_mfma_f32_16x16x32_bf16(a, b0[c], acc0, 0, 0, 0);
      acc1 = __builtin_amdgcn_mfma_f32_16x16x32_bf16(a, b1[c], acc1, 0, 0, 0);
    }
    if (lq == 0) {  // C row 0 lives in lanes 0..15, reg 0
      zs[nt0 * 16 + l16] = acc0[0];
      zs[nt1 * 16 + l16] = acc1[0];
    }
    LGKM_BARRIER();
    if (tid < 300) {
      float z = zs[tid] + gx_cur;
      float g = 1.f / (1.f + __expf(-z));
      m_reg = fmaf(g, p0_cur - m_reg, m_reg);   // g*p0 + (1-g)*m
      m_bf[tid] = f2b(m_reg);
      mr_s[(t & 7) * 320 + tid] = f2b(fmaxf(m_reg, 0.f));
    } else if (tid < 320) {
      mr_s[(t & 7) * 320 + tid] = 0;
    }
    LGKM_BARRIER();
    if ((t & 7) == 7) {  // flush 8 steps of Mrelu; stores stay in flight (no vmcnt drain)
      unsigned int* dst = (unsigned int*)(Mrelu_bf + (size_t)(t - 7) * 320);
      const unsigned int* src = (const unsigned int*)mr_s;
      for (int w = tid; w < 1280; w += 640) dst[w] = src[w];
    }
    gx_cur = gx_nxt; p0_cur = p0_nxt;
  }
}

// ---------------- in-place log_softmax per row + int32-zero tail ----------------
__global__ __launch_bounds__(256) void k_lsm(float* __restrict__ out) {
  const int t = blockIdx.x;
  float* row = out + (size_t)t * VG_;
  const f32x4* row4 = (const f32x4*)row;
  __shared__ float redM[256];
  __shared__ float redS[256];
  const int tid = threadIdx.x;
  float lm = -1e30f, ls = 0.f;
  for (int v = tid; v < VG_ / 4; v += 256) {
    f32x4 z4 = row4[v];
    #pragma unroll
    for (int j = 0; j < 4; ++j) {
      float z = z4[j];
      float m2 = fmaxf(lm, z);
      ls = ls * expf(lm - m2) + expf(z - m2);
      lm = m2;
    }
  }
  redM[tid] = lm; redS[tid] = ls;
  __syncthreads();
  for (int s = 128; s > 0; s >>= 1) {
    if (tid < s) {
      float mA = redM[tid], mB = redM[tid + s];
      float M = fmaxf(mA, mB);
      redS[tid] = redS[tid] * expf(mA - M) + redS[tid + s] * expf(mB - M);
      redM[tid] = M;
    }
    __syncthreads();
  }
  float lse = redM[0] + logf(redS[0]);
  f32x4* row4w = (f32x4*)row;
  for (int v = tid; v < VG_ / 4; v += 256) {
    f32x4 z4 = row4w[v];
    #pragma unroll
    for (int j = 0; j < 4; ++j) z4[j] -= lse;
    row4w[v] = z4;
  }
  if (tid == 0) out[(size_t)T_ * VG_ + t] = 0.0f;
}

// ---------------- launch ----------------
extern "C" void kernel_launch(void* const* d_in, const int* in_sizes, int n_in,
                              void* d_out, int out_size, void* d_ws, size_t ws_size,
                              hipStream_t stream) {
  const int*   xidx  = (const int*)d_in[0];
  const int*   esrc  = (const int*)d_in[1];
  const int*   edst  = (const int*)d_in[2];
  const float* X     = (const float*)d_in[3];
  const float* convW = (const float*)d_in[4];
  const float* W0    = (const float*)d_in[5];
  const float* Wu    = (const float*)d_in[6];
  const float* Uu    = (const float*)d_in[7];
  const float* Wg    = (const float*)d_in[8];
  const float* bg    = (const float*)d_in[9];
  float* out = (float*)d_out;

  // workspace layout (20.94 MB total, all 16B-aligned; proven ws >= 24.1 MB in R1)
  char* ws = (char*)d_ws;
  float*          gx     = (float*)ws;                              // 512*300 f32
  float*          P0     = (float*)(ws + 614400);                   // 512*300 f32
  unsigned short* MreluB = (unsigned short*)(ws + 1228800);         // 512*320 bf16
  unsigned short* xgB    = (unsigned short*)(ws + 1556480);         // 512*9600 bf16
  unsigned short* AgB    = (unsigned short*)(ws + 11386880);        // 512*1216 bf16
  unsigned short* WuT    = (unsigned short*)(ws + 12632064);        // 384*9600 bf16
  unsigned short* WcatT  = (unsigned short*)(ws + 20004864);        // 384*1216 bf16

  k_zero<<<(T_ * D_ + 255) / 256, 256, 0, stream>>>(gx, T_ * D_);
  k_tr_wu<<<dim3(300, 12), 256, 0, stream>>>(Wu, WuT);
  k_tr_wcat<<<dim3(38, 12), 256, 0, stream>>>(convW, W0, WcatT);
  k_gather<<<T_, 320, 0, stream>>>(xidx, esrc, edst, X, xgB, AgB);

  // gx = xg @ Wu   (split-K=10, atomic into zeroed gx)
  k_bgemm<true><<<dim3(4, 3, 10), 256, 0, stream>>>(xgB, WuT, gx, D_, D_, 9600, 960);
  // P0 = [Ag | x0] @ [convW; W0]
  k_bgemm<false><<<dim3(4, 3, 1), 256, 0, stream>>>(AgB, WcatT, P0, D_, D_, 1216, 1216);

  k_rec<<<1, 640, 0, stream>>>(gx, P0, Uu, MreluB);

  k_lgemm<<<dim3(625), 256, 0, stream>>>(MreluB, Wg, bg, out);
  k_lsm<<<T_, 256, 0, stream>>>(out);
}

// Round 4
// 889.475 us; speedup vs baseline: 2.5664x; 1.0021x over previous
//
#include <hip/hip_runtime.h>
#include <hip/hip_bf16.h>
#include <math.h>

#define T_ 512
#define N_ 32
#define D_ 300
#define R_ 3
#define E_ 64
#define VG_ 40000

typedef __attribute__((ext_vector_type(8))) short bf16x8;
typedef __attribute__((ext_vector_type(4))) float f32x4;

// barrier with lgkm-only wait requested (legalizer may still add vmcnt — see R3)
#define LGKM_BARRIER() asm volatile("s_waitcnt lgkmcnt(0)\n\ts_barrier" ::: "memory")

static __device__ inline unsigned short f2b(float f) {
  __hip_bfloat16 h = __float2bfloat16(f);
  return *(unsigned short*)&h;
}

// ---------------- zero ----------------
__global__ void k_zero(float* __restrict__ p, int n) {
  int i = blockIdx.x * blockDim.x + threadIdx.x;
  if (i < n) p[i] = 0.f;
}

// ---------------- transpose Wu [9600,300] -> Wu_t bf16 [384][9600] ----------------
__global__ void k_tr_wu(const float* __restrict__ Wu, unsigned short* __restrict__ Wt) {
  __shared__ float s[32][33];
  int kb = blockIdx.x * 32, nb = blockIdx.y * 32;
  int tn = threadIdx.x & 31, tr = threadIdx.x >> 5;  // 256 threads: tr 0..7
  for (int i = tr; i < 32; i += 8) {
    int k = kb + i, n = nb + tn;
    s[i][tn] = (n < 300) ? Wu[(size_t)k * 300 + n] : 0.f;
  }
  __syncthreads();
  for (int i = tr; i < 32; i += 8) {
    int n = nb + i, k = kb + tn;
    Wt[(size_t)n * 9600 + k] = f2b(s[tn][i]);
  }
}

// ---------------- transpose [convW;W0] [1200,300] -> Wcat_t bf16 [384][1216] ----------------
__global__ void k_tr_wcat(const float* __restrict__ convW, const float* __restrict__ W0,
                          unsigned short* __restrict__ Wt) {
  __shared__ float s[32][33];
  int kb = blockIdx.x * 32, nb = blockIdx.y * 32;
  int tn = threadIdx.x & 31, tr = threadIdx.x >> 5;
  for (int i = tr; i < 32; i += 8) {
    int k = kb + i, n = nb + tn;
    float v = 0.f;
    if (n < 300 && k < 1200)
      v = (k < 900) ? convW[(size_t)k * 300 + n] : W0[(size_t)(k - 900) * 300 + n];
    s[i][tn] = v;
  }
  __syncthreads();
  for (int i = tr; i < 32; i += 8) {
    int n = nb + i, k = kb + tn;
    Wt[(size_t)n * 1216 + k] = f2b(s[tn][i]);
  }
}

// ---------------- gather + node-0 aggregation (bf16 outputs) ----------------
__global__ void k_gather(const int* __restrict__ xidx, const int* __restrict__ esrc,
                         const int* __restrict__ edst, const float* __restrict__ X,
                         unsigned short* __restrict__ xg, unsigned short* __restrict__ Ag)
{
  const int t = blockIdx.x;
  __shared__ int s_idx[N_];
  __shared__ int s_src[R_][E_];
  __shared__ int s_dst[R_][E_];
  __shared__ int s_deg[R_][N_];
  __shared__ float s_dinv[R_][N_];
  const int tid = threadIdx.x;

  if (tid < N_) s_idx[tid] = xidx[t * N_ + tid];
  if (tid < R_ * E_) {
    int r = tid / E_, e = tid % E_;
    s_src[r][e] = esrc[(t * R_ + r) * E_ + e];
    s_dst[r][e] = edst[(t * R_ + r) * E_ + e];
  }
  if (tid < R_ * N_) ((int*)s_deg)[tid] = 1;  // self loop
  __syncthreads();
  if (tid < R_ * E_) {
    int r = tid / E_;
    atomicAdd(&s_deg[r][s_dst[r][tid % E_]], 1);
  }
  __syncthreads();
  if (tid < R_ * N_) ((float*)s_dinv)[tid] = rsqrtf((float)((int*)s_deg)[tid]);
  __syncthreads();

  for (int nd = tid; nd < N_ * D_; nd += blockDim.x) {
    int n = nd / D_, d = nd % D_;
    xg[(size_t)t * (N_ * D_) + nd] = f2b(X[(size_t)s_idx[n] * D_ + d]);
  }
  if (tid < D_) {
    int d = tid;
    float x0 = X[(size_t)s_idx[0] * D_ + d];
    #pragma unroll
    for (int r = 0; r < R_; ++r) {
      float dinv0 = s_dinv[r][0];
      float acc = dinv0 * dinv0 * x0;  // self loop
      for (int e = 0; e < E_; ++e) {
        if (s_dst[r][e] == 0) {
          int s = s_src[r][e];
          acc += s_dinv[r][s] * dinv0 * X[(size_t)s_idx[s] * D_ + d];
        }
      }
      Ag[(size_t)t * 1216 + r * D_ + d] = f2b(acc);
    }
    Ag[(size_t)t * 1216 + 900 + d] = f2b(x0);
  }
  if (tid < 16) Ag[(size_t)t * 1216 + 1200 + tid] = 0;  // K pad to 1216
}

// ---------------- bf16 MFMA GEMM: C (+)= A[M][K]bf16 @ B^T (B [Npad][K] bf16) ----------------
template<bool ATOMIC>
__global__ __launch_bounds__(256) void k_bgemm(
    const unsigned short* __restrict__ A,
    const unsigned short* __restrict__ B,
    float* __restrict__ C, int ldc, int Ncols, int K, int kchunk)
{
  const int tid = threadIdx.x;
  const int wid = tid >> 6, lane = tid & 63;
  const int l16 = lane & 15, lq = lane >> 4;
  const int bm = blockIdx.x * 128 + (wid & 1) * 64;
  const int bn = blockIdx.y * 128 + (wid >> 1) * 64;
  const int k0 = blockIdx.z * kchunk;
  const int nk = kchunk / 32;

  f32x4 acc[4][4] = {};
  const unsigned short* ap[4];
  const unsigned short* bp[4];
  #pragma unroll
  for (int mt = 0; mt < 4; ++mt) ap[mt] = A + (size_t)(bm + mt * 16 + l16) * K + k0 + lq * 8;
  #pragma unroll
  for (int nt = 0; nt < 4; ++nt) bp[nt] = B + (size_t)(bn + nt * 16 + l16) * K + k0 + lq * 8;

  #pragma unroll 2
  for (int c = 0; c < nk; ++c) {
    bf16x8 af[4], bfr[4];
    #pragma unroll
    for (int mt = 0; mt < 4; ++mt) af[mt] = *(const bf16x8*)(ap[mt] + c * 32);
    #pragma unroll
    for (int nt = 0; nt < 4; ++nt) bfr[nt] = *(const bf16x8*)(bp[nt] + c * 32);
    #pragma unroll
    for (int mt = 0; mt < 4; ++mt)
      #pragma unroll
      for (int nt = 0; nt < 4; ++nt)
        acc[mt][nt] = __builtin_amdgcn_mfma_f32_16x16x32_bf16(af[mt], bfr[nt], acc[mt][nt], 0, 0, 0);
  }

  #pragma unroll
  for (int mt = 0; mt < 4; ++mt) {
    #pragma unroll
    for (int r = 0; r < 4; ++r) {
      int row = bm + mt * 16 + lq * 4 + r;
      #pragma unroll
      for (int nt = 0; nt < 4; ++nt) {
        int col = bn + nt * 16 + l16;
        if (col < Ncols) {
          if (ATOMIC) atomicAdd(&C[(size_t)row * ldc + col], acc[mt][nt][r]);
          else        C[(size_t)row * ldc + col] = acc[mt][nt][r];
        }
      }
    }
  }
}

// ---------------- logits GEMM: out[512][40000] = Mrelu_bf[512][320] @ Wg^T + bg ----------------
// Single pass over Wg: each block owns 64 cols and ALL 512 rows (8 m-tiles/wave).
__global__ __launch_bounds__(256, 2) void k_lgemm(
    const unsigned short* __restrict__ A, const float* __restrict__ Wg,
    const float* __restrict__ bg, float* __restrict__ C)
{
  const int tid = threadIdx.x;
  const int wid = tid >> 6, lane = tid & 63;
  const int l16 = lane & 15, lq = lane >> 4;
  const int bn = blockIdx.x * 64;
  const int m0 = wid * 128;

  f32x4 acc[8][4] = {};
  const unsigned short* ap[8];
  const float* bp[4];
  #pragma unroll
  for (int mt = 0; mt < 8; ++mt) ap[mt] = A + (size_t)(m0 + mt * 16 + l16) * 320 + lq * 8;
  #pragma unroll
  for (int nt = 0; nt < 4; ++nt) bp[nt] = Wg + (size_t)(bn + nt * 16 + l16) * 300;

  #pragma unroll
  for (int c = 0; c < 10; ++c) {
    bf16x8 bfr[4];
    if (c < 9) {
      #pragma unroll
      for (int nt = 0; nt < 4; ++nt) {
        f32x4 x = *(const f32x4*)(bp[nt] + c * 32 + lq * 8);
        f32x4 y = *(const f32x4*)(bp[nt] + c * 32 + lq * 8 + 4);
        bf16x8 bv;
        #pragma unroll
        for (int j = 0; j < 4; ++j) { bv[j] = (short)f2b(x[j]); bv[4 + j] = (short)f2b(y[j]); }
        bfr[nt] = bv;
      }
    } else {
      #pragma unroll
      for (int nt = 0; nt < 4; ++nt) {
        bf16x8 bv;
        #pragma unroll
        for (int j = 0; j < 8; ++j) {
          int k = 288 + lq * 8 + j;
          bv[j] = (short)((k < 300) ? f2b(bp[nt][k]) : 0);
        }
        bfr[nt] = bv;
      }
    }
    bf16x8 af[8];
    #pragma unroll
    for (int mt = 0; mt < 8; ++mt) af[mt] = *(const bf16x8*)(ap[mt] + c * 32);
    #pragma unroll
    for (int mt = 0; mt < 8; ++mt)
      #pragma unroll
      for (int nt = 0; nt < 4; ++nt)
        acc[mt][nt] = __builtin_amdgcn_mfma_f32_16x16x32_bf16(af[mt], bfr[nt], acc[mt][nt], 0, 0, 0);
  }

  float bb[4];
  #pragma unroll
  for (int nt = 0; nt < 4; ++nt) bb[nt] = bg[bn + nt * 16 + l16];
  #pragma unroll
  for (int mt = 0; mt < 8; ++mt) {
    #pragma unroll
    for (int r = 0; r < 4; ++r) {
      int row = m0 + mt * 16 + lq * 4 + r;
      #pragma unroll
      for (int nt = 0; nt < 4; ++nt) {
        int col = bn + nt * 16 + l16;
        C[(size_t)row * VG_ + col] = acc[mt][nt][r] + bb[nt];
      }
    }
  }
}

// ---------------- sequential recurrence v3: 1 barrier/step, gate in-lane ----------------
// 10 waves; wave w owns n-tiles {2w,2w+1} = cols [32w,32w+32).
// z (MFMA C row 0) lives in lanes 0..15 reg 0 -> gate applied in-lane, m kept in
// registers of those lanes. m_bf double-buffered so a single end-of-step barrier
// both publishes new m and separates buffer reuse (reads of buf are retired
// before their wave hits the barrier, since MFMAs consumed them).
__global__ __launch_bounds__(640) void k_rec(
    const float* __restrict__ gx, const float* __restrict__ P0,
    const float* __restrict__ Uu, unsigned short* __restrict__ Mrelu_bf)
{
  __shared__ __align__(16) unsigned short m_bf[2][320];
  __shared__ unsigned short mr_s[16 * 320];  // 16-step Mrelu ring
  const int tid = threadIdx.x;
  const int wid = tid >> 6, lane = tid & 63;
  const int l16 = lane & 15, lq = lane >> 4;
  const int nt0 = wid * 2, nt1 = wid * 2 + 1;

  // preload B fragments: layout B[k=(lq*8+j)+32c][n=tile*16+l16]
  bf16x8 b0[10], b1[10];
  {
    int n0 = nt0 * 16 + l16, n1 = nt1 * 16 + l16;
    #pragma unroll
    for (int c = 0; c < 10; ++c) {
      bf16x8 v0, v1;
      #pragma unroll
      for (int j = 0; j < 8; ++j) {
        int k = c * 32 + lq * 8 + j;
        float f0 = (k < 300 && n0 < 300) ? Uu[(size_t)k * 300 + n0] : 0.f;
        float f1 = (k < 300 && n1 < 300) ? Uu[(size_t)k * 300 + n1] : 0.f;
        v0[j] = (short)f2b(f0);
        v1[j] = (short)f2b(f1);
      }
      b0[c] = v0; b1[c] = v1;
    }
  }

  // gate lanes: lanes 0..15 of each wave own cols c0, c1
  const int c0 = wid * 32 + l16;
  const int c1 = c0 + 16;
  const bool gate = (lq == 0);
  float m0 = 0.f, m1 = 0.f;
  float gx0 = 0.f, gx1 = 0.f, p00 = 0.f, p01 = 0.f;
  if (gate) {
    if (c0 < 300) { gx0 = gx[c0]; p00 = P0[c0]; }
    if (c1 < 300) { gx1 = gx[c1]; p01 = P0[c1]; }
  }

  if (tid < 320) { m_bf[0][tid] = 0; m_bf[1][tid] = 0; }
  for (int i = tid; i < 16 * 320; i += 640) mr_s[i] = 0;  // cols>=300 stay 0 forever
  __syncthreads();

  for (int t = 0; t < T_; ++t) {
    const int rb = t & 1, wb = rb ^ 1;
    // A fragments (broadcast reads of current m)
    bf16x8 a[10];
    #pragma unroll
    for (int c = 0; c < 10; ++c)
      a[c] = *(const bf16x8*)(&m_bf[rb][c * 32 + lq * 8]);
    // 4 interleaved MFMA chains (2 tiles x 2 k-halves)
    f32x4 A0 = {0.f,0.f,0.f,0.f}, A1 = {0.f,0.f,0.f,0.f};
    f32x4 B0 = {0.f,0.f,0.f,0.f}, B1 = {0.f,0.f,0.f,0.f};
    #pragma unroll
    for (int cc = 0; cc < 5; ++cc) {
      A0 = __builtin_amdgcn_mfma_f32_16x16x32_bf16(a[cc],     b0[cc],     A0, 0, 0, 0);
      A1 = __builtin_amdgcn_mfma_f32_16x16x32_bf16(a[cc],     b1[cc],     A1, 0, 0, 0);
      B0 = __builtin_amdgcn_mfma_f32_16x16x32_bf16(a[cc + 5], b0[cc + 5], B0, 0, 0, 0);
      B1 = __builtin_amdgcn_mfma_f32_16x16x32_bf16(a[cc + 5], b1[cc + 5], B1, 0, 0, 0);
    }
    if (gate) {
      const int slot = (t & 15) * 320;
      if (c0 < 300) {
        float z = A0[0] + B0[0] + gx0;
        float g = __frcp_rn(1.f + __expf(-z));
        m0 = fmaf(g, p00 - m0, m0);
        m_bf[wb][c0] = f2b(m0);
        mr_s[slot + c0] = f2b(fmaxf(m0, 0.f));
      }
      if (c1 < 300) {
        float z = A1[0] + B1[0] + gx1;
        float g = __frcp_rn(1.f + __expf(-z));
        m1 = fmaf(g, p01 - m1, m1);
        m_bf[wb][c1] = f2b(m1);
        mr_s[slot + c1] = f2b(fmaxf(m1, 0.f));
      }
      if (t + 1 < T_) {  // prefetch next step's gx/P0 (consumed next iteration)
        const size_t o = (size_t)(t + 1) * D_;
        if (c0 < 300) { gx0 = gx[o + c0]; p00 = P0[o + c0]; }
        if (c1 < 300) { gx1 = gx[o + c1]; p01 = P0[o + c1]; }
      }
    }
    LGKM_BARRIER();
    // flush 8 finished steps (rows t-7..t); slots disjoint from upcoming writes,
    // and this wave's flush reads retire at its next end-of-step barrier, 8 steps
    // before these slots are rewritten.
    if ((t & 7) == 7) {
      const int base = t - 7;
      const unsigned int* src = (const unsigned int*)(mr_s + (base & 15) * 320);
      unsigned int* dst = (unsigned int*)(Mrelu_bf + (size_t)base * 320);
      for (int w = tid; w < 1280; w += 640) dst[w] = src[w];
    }
  }
}

// ---------------- in-place log_softmax per row + int32-zero tail ----------------
__global__ __launch_bounds__(256) void k_lsm(float* __restrict__ out) {
  const int t = blockIdx.x;
  float* row = out + (size_t)t * VG_;
  const f32x4* row4 = (const f32x4*)row;
  __shared__ float redM[256];
  __shared__ float redS[256];
  const int tid = threadIdx.x;
  float lm = -1e30f, ls = 0.f;
  for (int v = tid; v < VG_ / 4; v += 256) {
    f32x4 z4 = row4[v];
    #pragma unroll
    for (int j = 0; j < 4; ++j) {
      float z = z4[j];
      float m2 = fmaxf(lm, z);
      ls = ls * expf(lm - m2) + expf(z - m2);
      lm = m2;
    }
  }
  redM[tid] = lm; redS[tid] = ls;
  __syncthreads();
  for (int s = 128; s > 0; s >>= 1) {
    if (tid < s) {
      float mA = redM[tid], mB = redM[tid + s];
      float M = fmaxf(mA, mB);
      redS[tid] = redS[tid] * expf(mA - M) + redS[tid + s] * expf(mB - M);
      redM[tid] = M;
    }
    __syncthreads();
  }
  float lse = redM[0] + logf(redS[0]);
  f32x4* row4w = (f32x4*)row;
  for (int v = tid; v < VG_ / 4; v += 256) {
    f32x4 z4 = row4w[v];
    #pragma unroll
    for (int j = 0; j < 4; ++j) z4[j] -= lse;
    row4w[v] = z4;
  }
  if (tid == 0) out[(size_t)T_ * VG_ + t] = 0.0f;
}

// ---------------- launch ----------------
extern "C" void kernel_launch(void* const* d_in, const int* in_sizes, int n_in,
                              void* d_out, int out_size, void* d_ws, size_t ws_size,
                              hipStream_t stream) {
  const int*   xidx  = (const int*)d_in[0];
  const int*   esrc  = (const int*)d_in[1];
  const int*   edst  = (const int*)d_in[2];
  const float* X     = (const float*)d_in[3];
  const float* convW = (const float*)d_in[4];
  const float* W0    = (const float*)d_in[5];
  const float* Wu    = (const float*)d_in[6];
  const float* Uu    = (const float*)d_in[7];
  const float* Wg    = (const float*)d_in[8];
  const float* bg    = (const float*)d_in[9];
  float* out = (float*)d_out;

  // workspace layout (20.94 MB total, all 16B-aligned)
  char* ws = (char*)d_ws;
  float*          gx     = (float*)ws;                              // 512*300 f32
  float*          P0     = (float*)(ws + 614400);                   // 512*300 f32
  unsigned short* MreluB = (unsigned short*)(ws + 1228800);         // 512*320 bf16
  unsigned short* xgB    = (unsigned short*)(ws + 1556480);         // 512*9600 bf16
  unsigned short* AgB    = (unsigned short*)(ws + 11386880);        // 512*1216 bf16
  unsigned short* WuT    = (unsigned short*)(ws + 12632064);        // 384*9600 bf16
  unsigned short* WcatT  = (unsigned short*)(ws + 20004864);        // 384*1216 bf16

  k_zero<<<(T_ * D_ + 255) / 256, 256, 0, stream>>>(gx, T_ * D_);
  k_tr_wu<<<dim3(300, 12), 256, 0, stream>>>(Wu, WuT);
  k_tr_wcat<<<dim3(38, 12), 256, 0, stream>>>(convW, W0, WcatT);
  k_gather<<<T_, 320, 0, stream>>>(xidx, esrc, edst, X, xgB, AgB);

  // gx = xg @ Wu   (split-K=10, atomic into zeroed gx)
  k_bgemm<true><<<dim3(4, 3, 10), 256, 0, stream>>>(xgB, WuT, gx, D_, D_, 9600, 960);
  // P0 = [Ag | x0] @ [convW; W0]
  k_bgemm<false><<<dim3(4, 3, 1), 256, 0, stream>>>(AgB, WcatT, P0, D_, D_, 1216, 1216);

  k_rec<<<1, 640, 0, stream>>>(gx, P0, Uu, MreluB);

  k_lgemm<<<dim3(625), 256, 0, stream>>>(MreluB, Wg, bg, out);
  k_lsm<<<T_, 256, 0, stream>>>(out);
}